// Round 16
// baseline (194.785 us; speedup 1.0000x reference)
//
#include <hip/hip_runtime.h>
#include <math.h>

#define L_SEQ 4096
#define D_HEAD 64
#define M_WIN 128
#define WIN 257              // 2*M+1
#define QB 8                 // q rows per block
#define W 264                // WIN + QB - 1
#define WF4 66               // W/4
#define ATTS 272             // padded att row stride (floats); f4 stride 68
#define SCALE 0.125f         // 1/sqrt(64)

// wave-uniform lane read via VALU (v_readlane -> SGPR), not LDS pipe
#define RL(v, i) __uint_as_float(__builtin_amdgcn_readlane(__float_as_uint(v), (i)))

static __device__ __forceinline__ unsigned bfr(float x) {      // f32->bf16 RNE
    unsigned u = __float_as_uint(x);
    return (u + 0x7fffu + ((u >> 16) & 1u)) >> 16;
}
static __device__ __forceinline__ unsigned bfpack(float lo, float hi) {
    return bfr(lo) | (bfr(hi) << 16);
}

// Block = 5 waves: waves 0-3 compute (round-14 pipeline, window-only stores),
// wave 4 = fill wave (streams the 8 rows' non-window zeros, no loads after
// stores -> nothing ever waits on them; they drain under B/C/E compute).
// K tile: [264 rows][8 uint4 slots], slot = c8 ^ (row&7); one uint4 = 8 bf16.
__global__ __launch_bounds__(320, 3) void win_attn_kernel(
    const float* __restrict__ Q, const float* __restrict__ K,
    const float* __restrict__ V, float* __restrict__ OutO,
    float* __restrict__ OutA)
{
    extern __shared__ float smem[];
    uint4* k_su = (uint4*)smem;              // [264][8] uint4 = 33792 B
    float* att  = smem + 2112 * 4;           // [QB][ATTS] = 8704 B

    const int t  = threadIdx.x;
    const int w  = t >> 6;                   // wave 0..4
    const int ln = t & 63;
    const int bid = blockIdx.x;              // native mapping (round-14 best)
    const int b   = bid >> 9;
    const int q0  = (bid & 511) * QB;

    int s0 = q0 - M_WIN;
    if (s0 < 0) s0 = 0;
    if (s0 > L_SEQ - WIN) s0 = L_SEQ - WIN;
    const int wcount = (L_SEQ - s0 < W) ? (L_SEQ - s0) : W;
    const int zlo = s0 >> 2;                             // window f4 start
    const int zhi = (s0 & 3) ? 1024 : (zlo + WF4);       // window f4 end

    // ---------------- Phase A: all 5 waves stage K (bf16, swizzled) ---------
    {
        const float4* Kg = (const float4*)(K + ((size_t)(b * L_SEQ + s0)) * D_HEAD);
        #pragma unroll 2
        for (int idx = t; idx < 264 * 8; idx += 320) {
            int row = idx >> 3, c8 = idx & 7;
            int gr  = (row < wcount) ? row : wcount - 1;
            float4 a  = Kg[(size_t)gr * 16 + c8 * 2];
            float4 bb = Kg[(size_t)gr * 16 + c8 * 2 + 1];
            uint4 d;
            d.x = bfpack(a.x, a.y);   d.y = bfpack(a.z, a.w);
            d.z = bfpack(bb.x, bb.y); d.w = bfpack(bb.z, bb.w);
            k_su[row * 8 + (c8 ^ (row & 7))] = d;
        }
    }
    const int r0g = q0 + 2 * w;              // compute waves' two global q rows
    float qv0 = 0.f, qv1 = 0.f;
    if (w < 4) {
        qv0 = Q[((size_t)(b * L_SEQ) + r0g)     * D_HEAD + ln];
        qv1 = Q[((size_t)(b * L_SEQ) + r0g + 1) * D_HEAD + ln];
        // zero the att row pad (cols 264..271) for vectorized phase E reads
        if (ln < 16) {
            int r = 2 * w + (ln >> 3);
            att[r * ATTS + 264 + (ln & 7)] = 0.f;
        }
    }
    __syncthreads();                         // the ONLY block-wide barrier

    if (w == 4) {
        // ---------------- Fill wave: stream non-window zeros, then exit -----
        const float4 z = {0.f, 0.f, 0.f, 0.f};
        #pragma unroll 4
        for (int idx = ln; idx < QB * 1024; idx += 64) {
            int ql  = idx >> 10;
            int f4i = idx & 1023;
            if (f4i < zlo || f4i >= zhi) {
                float4* rowp = (float4*)(OutA + ((size_t)(b * L_SEQ + q0 + ql)) * L_SEQ);
                rowp[f4i] = z;               // fire-and-forget, 1 KB/instr
            }
        }
        return;
    }

    // ---------------- Phase B: scores; lane owns cols cg*64+ln --------------
    float p0[5], p1[5];
    {
        const uint4* kp[5];
        int msk[5];
        #pragma unroll
        for (int cg = 0; cg < 5; ++cg) {
            int colr = cg * 64 + ln;
            int col  = (colr < W) ? colr : W - 1;   // clamped for memory
            kp[cg]  = k_su + (size_t)col * 8;
            msk[cg] = col & 7;
            p0[cg] = 0.f; p1[cg] = 0.f;
        }
        #pragma unroll
        for (int c8 = 0; c8 < 8; ++c8) {
            // q[8c8 .. 8c8+7] for both rows, via v_readlane (VALU, no LDS pipe)
            float a0 = RL(qv0, 8*c8+0), a1 = RL(qv0, 8*c8+1),
                  a2 = RL(qv0, 8*c8+2), a3 = RL(qv0, 8*c8+3),
                  a4 = RL(qv0, 8*c8+4), a5 = RL(qv0, 8*c8+5),
                  a6 = RL(qv0, 8*c8+6), a7 = RL(qv0, 8*c8+7);
            float b0 = RL(qv1, 8*c8+0), b1 = RL(qv1, 8*c8+1),
                  b2 = RL(qv1, 8*c8+2), b3 = RL(qv1, 8*c8+3),
                  b4 = RL(qv1, 8*c8+4), b5 = RL(qv1, 8*c8+5),
                  b6 = RL(qv1, 8*c8+6), b7 = RL(qv1, 8*c8+7);
            #pragma unroll
            for (int cg = 0; cg < 5; ++cg) {
                uint4 kk = kp[cg][c8 ^ msk[cg]];
                float e0 = __uint_as_float(kk.x << 16);
                float e1 = __uint_as_float(kk.x & 0xffff0000u);
                float e2 = __uint_as_float(kk.y << 16);
                float e3 = __uint_as_float(kk.y & 0xffff0000u);
                float e4 = __uint_as_float(kk.z << 16);
                float e5 = __uint_as_float(kk.z & 0xffff0000u);
                float e6 = __uint_as_float(kk.w << 16);
                float e7 = __uint_as_float(kk.w & 0xffff0000u);
                p0[cg] += a0*e0 + a1*e1 + a2*e2 + a3*e3
                        + a4*e4 + a5*e5 + a6*e6 + a7*e7;
                p1[cg] += b0*e0 + b1*e1 + b2*e2 + b3*e3
                        + b4*e4 + b5*e5 + b6*e6 + b7*e7;
            }
        }
        #pragma unroll
        for (int cg = 0; cg < 5; ++cg) { p0[cg] *= SCALE; p1[cg] *= SCALE; }
    }

    // ---------------- Phase C: in-register masked softmax (per wave) --------
    {
        int st0 = r0g - M_WIN;
        if (st0 < 0) st0 = 0;
        if (st0 > L_SEQ - WIN) st0 = L_SEQ - WIN;
        const int lo0 = st0 - s0;
        int st1 = r0g + 1 - M_WIN;
        if (st1 < 0) st1 = 0;
        if (st1 > L_SEQ - WIN) st1 = L_SEQ - WIN;
        const int lo1 = st1 - s0;

        float m0 = -1e30f, m1 = -1e30f;
        #pragma unroll
        for (int cg = 0; cg < 5; ++cg) {
            int colr = cg * 64 + ln;
            bool in0 = (colr >= lo0) && (colr < lo0 + WIN);
            bool in1 = (colr >= lo1) && (colr < lo1 + WIN);
            p0[cg] = in0 ? p0[cg] : -1e30f;
            p1[cg] = in1 ? p1[cg] : -1e30f;
            m0 = fmaxf(m0, p0[cg]);
            m1 = fmaxf(m1, p1[cg]);
        }
        #pragma unroll
        for (int off = 32; off >= 1; off >>= 1) {
            m0 = fmaxf(m0, __shfl_xor(m0, off));
            m1 = fmaxf(m1, __shfl_xor(m1, off));
        }
        float sum0 = 0.f, sum1 = 0.f;
        #pragma unroll
        for (int cg = 0; cg < 5; ++cg) {
            float e0 = (p0[cg] <= -1e29f) ? 0.f : __expf(p0[cg] - m0);
            float e1 = (p1[cg] <= -1e29f) ? 0.f : __expf(p1[cg] - m1);
            p0[cg] = e0; p1[cg] = e1;
            sum0 += e0; sum1 += e1;
        }
        #pragma unroll
        for (int off = 32; off >= 1; off >>= 1) {
            sum0 += __shfl_xor(sum0, off);
            sum1 += __shfl_xor(sum1, off);
        }
        const float inv0 = 1.f / sum0, inv1 = 1.f / sum1;
        #pragma unroll
        for (int cg = 0; cg < 5; ++cg) {
            int colr = cg * 64 + ln;
            if (colr < W) {
                att[(2 * w)     * ATTS + colr] = p0[cg] * inv0;  // 0 outside win
                att[(2 * w + 1) * ATTS + colr] = p1[cg] * inv1;
            }
        }
    }
    // No barrier: everything below reads only this wave's own att rows.

    // ---------------- Phase E: PV; vectorized att reads (b128 per 4 cols) ---
    {
        const int cq = ln >> 4;              // which f4 of the 16-col group
        const int dg = ln & 15;              // d float4-group
        const float4* Vg4 = (const float4*)(V + ((size_t)(b * L_SEQ + s0)) * D_HEAD);
        const float4* a4r0 = (const float4*)(att + (2 * w) * ATTS);
        const float4* a4r1 = (const float4*)(att + (2 * w + 1) * ATTS);
        float4 acc0 = {0.f,0.f,0.f,0.f}, acc1 = {0.f,0.f,0.f,0.f};
        #pragma unroll 2
        for (int G = 0; G < 17; ++G) {       // 17*16 = 272 cols (pad p = 0)
            float4 pa = a4r0[4 * G + cq];
            float4 pb = a4r1[4 * G + cq];
            #pragma unroll
            for (int e = 0; e < 4; ++e) {
                int col  = 16 * G + 4 * cq + e;
                int colc = (col < wcount) ? col : wcount - 1;   // p is 0 there
                float4 vv = Vg4[(size_t)colc * 16 + dg];
                float fa = (e == 0) ? pa.x : (e == 1) ? pa.y : (e == 2) ? pa.z : pa.w;
                float fb = (e == 0) ? pb.x : (e == 1) ? pb.y : (e == 2) ? pb.z : pb.w;
                acc0.x += fa * vv.x; acc0.y += fa * vv.y;
                acc0.z += fa * vv.z; acc0.w += fa * vv.w;
                acc1.x += fb * vv.x; acc1.y += fb * vv.y;
                acc1.z += fb * vv.z; acc1.w += fb * vv.w;
            }
        }
        #pragma unroll
        for (int off = 16; off <= 32; off <<= 1) {
            acc0.x += __shfl_xor(acc0.x, off); acc0.y += __shfl_xor(acc0.y, off);
            acc0.z += __shfl_xor(acc0.z, off); acc0.w += __shfl_xor(acc0.w, off);
            acc1.x += __shfl_xor(acc1.x, off); acc1.y += __shfl_xor(acc1.y, off);
            acc1.z += __shfl_xor(acc1.z, off); acc1.w += __shfl_xor(acc1.w, off);
        }
        if (ln < 16) {
            float4* o4 = (float4*)(OutO + ((size_t)(b * L_SEQ + r0g)) * D_HEAD);
            o4[dg]      = acc0;
            o4[16 + dg] = acc1;
        }
    }

    // ---------------- Phase D: window-only stores for this wave's 2 rows ----
    if ((s0 & 3) == 0) {
        #pragma unroll
        for (int r = 0; r < 2; ++r) {
            float4* rowp = (float4*)(OutA + ((size_t)(b * L_SEQ + r0g + r)) * L_SEQ);
            const float4* arow = (const float4*)(att + (2 * w + r) * ATTS);
            for (int i = ln; i < WF4; i += 64)
                rowp[zlo + i] = arow[i];     // 66 f4 per row
        }
    } else {   // rare top-edge blocks (s0 = 3839): window f4 span [959, 1024)
        #pragma unroll
        for (int r = 0; r < 2; ++r) {
            float4* rowp = (float4*)(OutA + ((size_t)(b * L_SEQ + r0g + r)) * L_SEQ);
            const float* arow = att + (2 * w + r) * ATTS;
            for (int i = ln; i < 65; i += 64) {
                int f4i = 959 + i;
                int u   = 4 * f4i - s0;
                float4 wv;
                wv.x = (u     >= 0 && u     < W) ? arow[u]     : 0.f;
                wv.y = (u + 1 >= 0 && u + 1 < W) ? arow[u + 1] : 0.f;
                wv.z = (u + 2 >= 0 && u + 2 < W) ? arow[u + 2] : 0.f;
                wv.w = (u + 3 >= 0 && u + 3 < W) ? arow[u + 3] : 0.f;
                rowp[f4i] = wv;
            }
        }
    }
}

extern "C" void kernel_launch(void* const* d_in, const int* in_sizes, int n_in,
                              void* d_out, int out_size, void* d_ws, size_t ws_size,
                              hipStream_t stream) {
    const float* Q = (const float*)d_in[0];
    const float* K = (const float*)d_in[1];
    const float* V = (const float*)d_in[2];
    float* OutO = (float*)d_out;
    float* OutA = OutO + (size_t)8 * L_SEQ * D_HEAD;

    const int smem_bytes = 2112 * 16 + QB * ATTS * 4;   // 42496 B
    hipFuncSetAttribute((const void*)win_attn_kernel,
                        hipFuncAttributeMaxDynamicSharedMemorySize, smem_bytes);

    dim3 grid(8 * (L_SEQ / QB));    // 4096 blocks
    dim3 block(320);                // 4 compute waves + 1 fill wave
    win_attn_kernel<<<grid, block, smem_bytes, stream>>>(Q, K, V, OutO, OutA);
}

// Round 17
// 160.866 us; speedup vs baseline: 1.2109x; 1.2109x over previous
//
#include <hip/hip_runtime.h>
#include <math.h>

#define L_SEQ 4096
#define D_HEAD 64
#define M_WIN 128
#define WIN 257              // 2*M+1
#define QB 8                 // q rows per block
#define W 264                // WIN + QB - 1
#define WF4 66               // W/4
#define ATTS 272             // att row stride (bf16 elements); b64 stride 68
#define SCALE 0.125f         // 1/sqrt(64)

// wave-uniform lane read via VALU (v_readlane -> SGPR), not LDS pipe
#define RL(v, i) __uint_as_float(__builtin_amdgcn_readlane(__float_as_uint(v), (i)))

static __device__ __forceinline__ unsigned bfr(float x) {      // f32->bf16 RNE
    unsigned u = __float_as_uint(x);
    return (u + 0x7fffu + ((u >> 16) & 1u)) >> 16;
}
static __device__ __forceinline__ unsigned bfpack(float lo, float hi) {
    return bfr(lo) | (bfr(hi) << 16);
}
static __device__ __forceinline__ float bf2f(unsigned h) {     // bf16->f32
    return __uint_as_float(h << 16);
}

// K tile: [264 rows][8 uint4 slots], slot = c8 ^ (row&7); one uint4 = 8 bf16.
// att tile: [QB][272] bf16 (4352 B) -> total LDS 38144 B -> 4 blocks/CU.
__global__ __launch_bounds__(256, 4) void win_attn_kernel(
    const float* __restrict__ Q, const float* __restrict__ K,
    const float* __restrict__ V, float* __restrict__ OutO,
    float* __restrict__ OutA)
{
    extern __shared__ float smem[];
    uint4*  k_su  = (uint4*)smem;            // [264][8] uint4 = 33792 B
    unsigned short* att_h = (unsigned short*)(smem + 2112 * 4);  // [QB][ATTS] bf16

    const int t  = threadIdx.x;
    const int w  = t >> 6;                   // wave 0..3 -> q rows {2w, 2w+1}
    const int ln = t & 63;
    const int bid = blockIdx.x;              // native mapping (round-14 best)
    const int b   = bid >> 9;
    const int q0  = (bid & 511) * QB;

    int s0 = q0 - M_WIN;
    if (s0 < 0) s0 = 0;
    if (s0 > L_SEQ - WIN) s0 = L_SEQ - WIN;
    const int wcount = (L_SEQ - s0 < W) ? (L_SEQ - s0) : W;

    // ---------------- Phase A: stage K (bf16, swizzled); q rows -> registers
    {
        const float4* Kg = (const float4*)(K + ((size_t)(b * L_SEQ + s0)) * D_HEAD);
        #pragma unroll 3
        for (int idx = t; idx < 264 * 8; idx += 256) {
            int row = idx >> 3, c8 = idx & 7;
            int gr  = (row < wcount) ? row : wcount - 1;
            float4 a  = Kg[(size_t)gr * 16 + c8 * 2];
            float4 bb = Kg[(size_t)gr * 16 + c8 * 2 + 1];
            uint4 d;
            d.x = bfpack(a.x, a.y);   d.y = bfpack(a.z, a.w);
            d.z = bfpack(bb.x, bb.y); d.w = bfpack(bb.z, bb.w);
            k_su[row * 8 + (c8 ^ (row & 7))] = d;
        }
    }
    const int r0g = q0 + 2 * w;              // this wave's two global q rows
    const float qv0 = Q[((size_t)(b * L_SEQ) + r0g)     * D_HEAD + ln];
    const float qv1 = Q[((size_t)(b * L_SEQ) + r0g + 1) * D_HEAD + ln];
    // zero the att row pad (cols 264..271) for vectorized phase E reads
    if (ln < 16) {
        int r = 2 * w + (ln >> 3);
        att_h[r * ATTS + 264 + (ln & 7)] = 0;
    }
    __syncthreads();                         // the ONLY block-wide barrier

    // ---------------- Phase B: scores; lane owns cols cg*64+ln --------------
    float p0[5], p1[5];
    {
        const uint4* kp[5];
        int msk[5];
        #pragma unroll
        for (int cg = 0; cg < 5; ++cg) {
            int colr = cg * 64 + ln;
            int col  = (colr < W) ? colr : W - 1;   // clamped for memory
            kp[cg]  = k_su + (size_t)col * 8;
            msk[cg] = col & 7;
            p0[cg] = 0.f; p1[cg] = 0.f;
        }
        #pragma unroll
        for (int c8 = 0; c8 < 8; ++c8) {
            // q[8c8 .. 8c8+7] for both rows, via v_readlane (VALU, no LDS pipe)
            float a0 = RL(qv0, 8*c8+0), a1 = RL(qv0, 8*c8+1),
                  a2 = RL(qv0, 8*c8+2), a3 = RL(qv0, 8*c8+3),
                  a4 = RL(qv0, 8*c8+4), a5 = RL(qv0, 8*c8+5),
                  a6 = RL(qv0, 8*c8+6), a7 = RL(qv0, 8*c8+7);
            float b0 = RL(qv1, 8*c8+0), b1 = RL(qv1, 8*c8+1),
                  b2 = RL(qv1, 8*c8+2), b3 = RL(qv1, 8*c8+3),
                  b4 = RL(qv1, 8*c8+4), b5 = RL(qv1, 8*c8+5),
                  b6 = RL(qv1, 8*c8+6), b7 = RL(qv1, 8*c8+7);
            #pragma unroll
            for (int cg = 0; cg < 5; ++cg) {
                uint4 kk = kp[cg][c8 ^ msk[cg]];
                float e0 = __uint_as_float(kk.x << 16);
                float e1 = __uint_as_float(kk.x & 0xffff0000u);
                float e2 = __uint_as_float(kk.y << 16);
                float e3 = __uint_as_float(kk.y & 0xffff0000u);
                float e4 = __uint_as_float(kk.z << 16);
                float e5 = __uint_as_float(kk.z & 0xffff0000u);
                float e6 = __uint_as_float(kk.w << 16);
                float e7 = __uint_as_float(kk.w & 0xffff0000u);
                p0[cg] += a0*e0 + a1*e1 + a2*e2 + a3*e3
                        + a4*e4 + a5*e5 + a6*e6 + a7*e7;
                p1[cg] += b0*e0 + b1*e1 + b2*e2 + b3*e3
                        + b4*e4 + b5*e5 + b6*e6 + b7*e7;
            }
        }
        #pragma unroll
        for (int cg = 0; cg < 5; ++cg) { p0[cg] *= SCALE; p1[cg] *= SCALE; }
    }

    // ---------------- Phase C: in-register masked softmax (per wave) --------
    {
        int st0 = r0g - M_WIN;
        if (st0 < 0) st0 = 0;
        if (st0 > L_SEQ - WIN) st0 = L_SEQ - WIN;
        const int lo0 = st0 - s0;
        int st1 = r0g + 1 - M_WIN;
        if (st1 < 0) st1 = 0;
        if (st1 > L_SEQ - WIN) st1 = L_SEQ - WIN;
        const int lo1 = st1 - s0;

        float m0 = -1e30f, m1 = -1e30f;
        #pragma unroll
        for (int cg = 0; cg < 5; ++cg) {
            int colr = cg * 64 + ln;
            bool in0 = (colr >= lo0) && (colr < lo0 + WIN);
            bool in1 = (colr >= lo1) && (colr < lo1 + WIN);
            p0[cg] = in0 ? p0[cg] : -1e30f;
            p1[cg] = in1 ? p1[cg] : -1e30f;
            m0 = fmaxf(m0, p0[cg]);
            m1 = fmaxf(m1, p1[cg]);
        }
        #pragma unroll
        for (int off = 32; off >= 1; off >>= 1) {
            m0 = fmaxf(m0, __shfl_xor(m0, off));
            m1 = fmaxf(m1, __shfl_xor(m1, off));
        }
        float sum0 = 0.f, sum1 = 0.f;
        #pragma unroll
        for (int cg = 0; cg < 5; ++cg) {
            float e0 = (p0[cg] <= -1e29f) ? 0.f : __expf(p0[cg] - m0);
            float e1 = (p1[cg] <= -1e29f) ? 0.f : __expf(p1[cg] - m1);
            p0[cg] = e0; p1[cg] = e1;
            sum0 += e0; sum1 += e1;
        }
        #pragma unroll
        for (int off = 32; off >= 1; off >>= 1) {
            sum0 += __shfl_xor(sum0, off);
            sum1 += __shfl_xor(sum1, off);
        }
        const float inv0 = 1.f / sum0, inv1 = 1.f / sum1;
        #pragma unroll
        for (int cg = 0; cg < 5; ++cg) {
            int colr = cg * 64 + ln;
            if (colr < W) {
                att_h[(2 * w)     * ATTS + colr] = (unsigned short)bfr(p0[cg] * inv0);
                att_h[(2 * w + 1) * ATTS + colr] = (unsigned short)bfr(p1[cg] * inv1);
            }
        }
    }
    // No barrier: everything below reads only this wave's own att rows.

    // ---------------- Phase E: PV; b64 att reads (4 bf16 p per read) --------
    {
        const int cq = ln >> 4;              // which 4-col group of 16
        const int dg = ln & 15;              // d float4-group
        const float4* Vg4 = (const float4*)(V + ((size_t)(b * L_SEQ + s0)) * D_HEAD);
        const uint2* a2r0 = (const uint2*)(att_h + (2 * w) * ATTS);
        const uint2* a2r1 = (const uint2*)(att_h + (2 * w + 1) * ATTS);
        float4 acc0 = {0.f,0.f,0.f,0.f}, acc1 = {0.f,0.f,0.f,0.f};
        #pragma unroll 2
        for (int G = 0; G < 17; ++G) {       // 17*16 = 272 cols (pad p = 0)
            uint2 ua = a2r0[4 * G + cq];     // 4 bf16 p-values
            uint2 ub = a2r1[4 * G + cq];
            float pa[4], pb[4];
            pa[0] = bf2f(ua.x & 0xffffu); pa[1] = bf2f(ua.x >> 16);
            pa[2] = bf2f(ua.y & 0xffffu); pa[3] = bf2f(ua.y >> 16);
            pb[0] = bf2f(ub.x & 0xffffu); pb[1] = bf2f(ub.x >> 16);
            pb[2] = bf2f(ub.y & 0xffffu); pb[3] = bf2f(ub.y >> 16);
            #pragma unroll
            for (int e = 0; e < 4; ++e) {
                int col  = 16 * G + 4 * cq + e;
                int colc = (col < wcount) ? col : wcount - 1;   // p is 0 there
                float4 vv = Vg4[(size_t)colc * 16 + dg];
                float fa = pa[e], fb = pb[e];
                acc0.x += fa * vv.x; acc0.y += fa * vv.y;
                acc0.z += fa * vv.z; acc0.w += fa * vv.w;
                acc1.x += fb * vv.x; acc1.y += fb * vv.y;
                acc1.z += fb * vv.z; acc1.w += fb * vv.w;
            }
        }
        #pragma unroll
        for (int off = 16; off <= 32; off <<= 1) {
            acc0.x += __shfl_xor(acc0.x, off); acc0.y += __shfl_xor(acc0.y, off);
            acc0.z += __shfl_xor(acc0.z, off); acc0.w += __shfl_xor(acc0.w, off);
            acc1.x += __shfl_xor(acc1.x, off); acc1.y += __shfl_xor(acc1.y, off);
            acc1.z += __shfl_xor(acc1.z, off); acc1.w += __shfl_xor(acc1.w, off);
        }
        if (ln < 16) {
            float4* o4 = (float4*)(OutO + ((size_t)(b * L_SEQ + r0g)) * D_HEAD);
            o4[dg]      = acc0;
            o4[16 + dg] = acc1;
        }
    }

    // ---------------- Phase D: dense stream of this wave's 2 att rows -------
    if ((s0 & 3) == 0) {
        const int zlo = s0 >> 2;
        #pragma unroll
        for (int r = 0; r < 2; ++r) {
            float4* rowp = (float4*)(OutA + ((size_t)(b * L_SEQ + r0g + r)) * L_SEQ);
            const uint2* arow = (const uint2*)(att_h + (2 * w + r) * ATTS);
            #pragma unroll 4
            for (int j = 0; j < 16; ++j) {
                int f4i = j * 64 + ln;
                int u4  = f4i - zlo;
                float4 wv = {0.f,0.f,0.f,0.f};
                if (u4 >= 0 && u4 < WF4) {
                    uint2 uu = arow[u4];                 // 4 bf16 -> f32
                    wv.x = bf2f(uu.x & 0xffffu); wv.y = bf2f(uu.x >> 16);
                    wv.z = bf2f(uu.y & 0xffffu); wv.w = bf2f(uu.y >> 16);
                }
                rowp[f4i] = wv;                          // 1 KB/instr, clean
            }
        }
    } else {   // rare top-edge blocks (s0 = 3839)
        #pragma unroll
        for (int r = 0; r < 2; ++r) {
            float4* rowp = (float4*)(OutA + ((size_t)(b * L_SEQ + r0g + r)) * L_SEQ);
            const unsigned short* arow = att_h + (2 * w + r) * ATTS;
            #pragma unroll 2
            for (int j = 0; j < 16; ++j) {
                int f4i = j * 64 + ln;
                int u   = 4 * f4i - s0;
                float4 wv;
                wv.x = (u     >= 0 && u     < W) ? bf2f(arow[u])     : 0.f;
                wv.y = (u + 1 >= 0 && u + 1 < W) ? bf2f(arow[u + 1]) : 0.f;
                wv.z = (u + 2 >= 0 && u + 2 < W) ? bf2f(arow[u + 2]) : 0.f;
                wv.w = (u + 3 >= 0 && u + 3 < W) ? bf2f(arow[u + 3]) : 0.f;
                rowp[f4i] = wv;
            }
        }
    }
}

extern "C" void kernel_launch(void* const* d_in, const int* in_sizes, int n_in,
                              void* d_out, int out_size, void* d_ws, size_t ws_size,
                              hipStream_t stream) {
    const float* Q = (const float*)d_in[0];
    const float* K = (const float*)d_in[1];
    const float* V = (const float*)d_in[2];
    float* OutO = (float*)d_out;
    float* OutA = OutO + (size_t)8 * L_SEQ * D_HEAD;

    const int smem_bytes = 2112 * 16 + QB * ATTS * 2;   // 38144 B -> 4 blk/CU
    hipFuncSetAttribute((const void*)win_attn_kernel,
                        hipFuncAttributeMaxDynamicSharedMemorySize, smem_bytes);

    dim3 grid(8 * (L_SEQ / QB));    // 4096 blocks
    dim3 block(256);
    win_attn_kernel<<<grid, block, smem_bytes, stream>>>(Q, K, V, OutO, OutA);
}